// Round 8
// baseline (548.810 us; speedup 1.0000x reference)
//
#include <hip/hip_runtime.h>
#include <math.h>

#define BB 32
#define NIN 2048
#define NOUT 64
#define DD 16

// ---- persistent kernel geometry ----
#define NBLK 256          // 1 block per CU (cooperative)
#define TPB 512           // 8 waves
#define BLKS_PER_B 8      // NBLK / BB
#define ROWS_PER_BLK 256  // NIN / BLKS_PER_B
#define ROWS_PER_WAVE 32
#define REG_ROWS 16       // rows held in VGPRs per wave (16*8=128 VGPRs)
#define LDS_ROWS 7        // rows in LDS per wave (56/block = 112 KB)
#define WS_ROWS 9         // rows re-read from ws fp16 per wave

#define LDS_DATA_UINTS (8 * LDS_ROWS * 512)           // 114688 B
#define DYN_LDS_BYTES (LDS_DATA_UINTS * 4 + 8 * 4 * 64 * 16)  // +32KB red = 147456

typedef float f4 __attribute__((ext_vector_type(4)));
typedef float f2 __attribute__((ext_vector_type(2)));
typedef _Float16 h2 __attribute__((ext_vector_type(2)));
typedef unsigned int u32;

#define AS __HIP_MEMORY_SCOPE_AGENT

__device__ __forceinline__ u32 packh2(float a, float b) {
    h2 h = { (_Float16)a, (_Float16)b };
    u32 u; __builtin_memcpy(&u, &h, 4); return u;
}
__device__ __forceinline__ f2 unph2(u32 u) {
    h2 h; __builtin_memcpy(&h, &u, 4);
    return __builtin_convertvector(h, f2);
}
__device__ __forceinline__ void ast(float* p, float v) {
    __hip_atomic_store(p, v, __ATOMIC_RELAXED, AS);
}
__device__ __forceinline__ float ald(float* p) {
    return __hip_atomic_load(p, __ATOMIC_RELAXED, AS);
}

// softmax-weighted accumulate for one row; lane == n_out, xx/vl/acc are d=0..15
__device__ __forceinline__ void soft_acc(const float (&xx)[16], const float (&vl)[16],
                                         float (&acc)[16]) {
    float l = 0.f;
    #pragma unroll
    for (int d = 0; d < 16; ++d) l = fmaf(xx[d], vl[d], l);
    const float e = __expf(l);      // max-free: |l| <= ~24, safe in f32
    float p = e;
    #pragma unroll
    for (int o = 1; o <= 32; o <<= 1) p += __shfl_xor(p, o);
    const float a = e * __builtin_amdgcn_rcpf(p);
    #pragma unroll
    for (int d = 0; d < 16; ++d) acc[d] = fmaf(xx[d], a, acc[d]);
}

// block-reduce acc -> partials; count arrivals; last block reduces batch,
// squashes, stores v (atomic) or out (plain), raises flag.
__device__ __forceinline__ void phase_epilogue(
    float (&acc)[16], f4* red, float* pX, int* cnt, int* flag,
    const float* bias, float* vdst, float scale, bool plainOut,
    int b, int blk, int tid, int lane, int w, float* n2s, int& sLast)
{
    __syncthreads();   // red reuse guard
    #pragma unroll
    for (int k = 0; k < 4; ++k)
        red[(w * 4 + k) * 64 + lane] = f4{acc[4*k], acc[4*k+1], acc[4*k+2], acc[4*k+3]};
    __syncthreads();
    if (tid < 256) {
        f4 s = red[tid];
        #pragma unroll
        for (int ww = 1; ww < 8; ++ww) s += red[ww * 256 + tid];
        float* dst = pX + (size_t)blk * 1024 + tid * 4;
        ast(dst, s.x); ast(dst + 1, s.y); ast(dst + 2, s.z); ast(dst + 3, s.w);
    }
    __syncthreads();   // drains vmcnt: all atomic stores complete
    if (tid == 0) {
        int old = __hip_atomic_fetch_add(&cnt[b], 1, __ATOMIC_ACQ_REL, AS);
        sLast = (old == BLKS_PER_B - 1);
    }
    __syncthreads();
    if (sLast) {       // block-uniform branch
        f4 s = f4{0.f, 0.f, 0.f, 0.f};
        const int n = tid & 63, k = tid >> 6;
        if (tid < 256) {
            #pragma unroll
            for (int cb = 0; cb < BLKS_PER_B; ++cb) {
                float* src = pX + (size_t)(b * BLKS_PER_B + cb) * 1024 + tid * 4;
                s += f4{ald(src), ald(src + 1), ald(src + 2), ald(src + 3)};
            }
            const f4 bi = *(const f4*)(bias + n * 16 + 4 * k);
            s = s * scale + bi;
            n2s[tid] = s.x*s.x + s.y*s.y + s.z*s.z + s.w*s.w;
        }
        __syncthreads();
        if (tid < 256) {
            const float n2 = n2s[n] + n2s[64 + n] + n2s[128 + n] + n2s[192 + n];
            const float kf = n2 / ((1.f + n2) * sqrtf(n2 + 1e-7f));
            s *= kf;
            float* d = vdst + (size_t)b * 1024 + n * 16 + 4 * k;
            if (plainOut) *(f4*)d = s;
            else { ast(d, s.x); ast(d + 1, s.y); ast(d + 2, s.z); ast(d + 3, s.w); }
        }
        __syncthreads();   // drain v stores before flag
        if (flag && tid == 0)
            __hip_atomic_store(&flag[b], 1, __ATOMIC_RELEASE, AS);
    }
}

__device__ __forceinline__ void wait_flag(int* flag, int b, int tid) {
    if (tid == 0) {
        int guard = 0;
        while (__hip_atomic_load(&flag[b], __ATOMIC_ACQUIRE, AS) == 0 &&
               ++guard < (1 << 22))
            __builtin_amdgcn_s_sleep(16);
    }
    __syncthreads();
}

__device__ __forceinline__ void weighted_phase(
    const u32 (&xr)[REG_ROWS][8], const u32* ldsU, const u32* xh,
    const float (&vl)[16], float (&acc)[16], int blk, int w, int lane)
{
    #pragma unroll
    for (int d = 0; d < 16; ++d) acc[d] = 0.f;
    #pragma unroll
    for (int i = 0; i < REG_ROWS; ++i) {
        float xx[16];
        #pragma unroll
        for (int kk = 0; kk < 8; ++kk) {
            f2 t = unph2(xr[i][kk]); xx[2*kk] = t.x; xx[2*kk+1] = t.y;
        }
        soft_acc(xx, vl, acc);
    }
    #pragma unroll
    for (int i = 0; i < LDS_ROWS; ++i) {
        const int slot = w * LDS_ROWS + i;
        float xx[16];
        #pragma unroll
        for (int kk = 0; kk < 8; ++kk) {
            f2 t = unph2(ldsU[slot * 512 + kk * 64 + lane]);
            xx[2*kk] = t.x; xx[2*kk+1] = t.y;
        }
        soft_acc(xx, vl, acc);
    }
    #pragma unroll
    for (int i = 0; i < WS_ROWS; ++i) {
        const u32* gp = xh + ((size_t)(blk * 8 + w) * WS_ROWS + i) * 512 + lane;
        u32 u[8];
        #pragma unroll
        for (int kk = 0; kk < 8; ++kk) u[kk] = gp[kk * 64];
        float xx[16];
        #pragma unroll
        for (int kk = 0; kk < 8; ++kk) {
            f2 t = unph2(u[kk]); xx[2*kk] = t.x; xx[2*kk+1] = t.y;
        }
        soft_acc(xx, vl, acc);
    }
}

__global__ __launch_bounds__(TPB, 2) void router_persistent(
    const float* __restrict__ x, const float* __restrict__ bias,
    float* __restrict__ out,
    int* cnt0, int* cnt1, int* cnt2, int* flag0, int* flag1,
    float* vbuf0, float* vbuf1, float* pA, float* pB, float* pC,
    u32* __restrict__ xh)
{
    extern __shared__ u32 smem[];
    u32* ldsU = smem;
    f4*  red  = (f4*)(smem + LDS_DATA_UINTS);
    __shared__ float n2s[256];
    __shared__ int sLast;

    const int blk = blockIdx.x;
    const int b   = blk / BLKS_PER_B;
    const int cb  = blk % BLKS_PER_B;
    const int tid = threadIdx.x;
    const int lane = tid & 63, w = tid >> 6;

    const size_t rowBase = (size_t)(b * NIN + cb * ROWS_PER_BLK);

    u32 xr[REG_ROWS][8];
    float acc[16];
    #pragma unroll
    for (int d = 0; d < 16; ++d) acc[d] = 0.f;

    // ---------------- phase 0: read f32 once, plain sum, stash fp16 ----------------
    #pragma unroll
    for (int i = 0; i < REG_ROWS; ++i) {
        const int row = w * ROWS_PER_WAVE + i;
        const float* rp = x + (rowBase + row) * 1024 + lane * 16;
        f4 a0 = __builtin_nontemporal_load((const f4*)rp);
        f4 a1 = __builtin_nontemporal_load((const f4*)(rp + 4));
        f4 a2 = __builtin_nontemporal_load((const f4*)(rp + 8));
        f4 a3 = __builtin_nontemporal_load((const f4*)(rp + 12));
        acc[0]+=a0.x; acc[1]+=a0.y; acc[2]+=a0.z; acc[3]+=a0.w;
        acc[4]+=a1.x; acc[5]+=a1.y; acc[6]+=a1.z; acc[7]+=a1.w;
        acc[8]+=a2.x; acc[9]+=a2.y; acc[10]+=a2.z; acc[11]+=a2.w;
        acc[12]+=a3.x; acc[13]+=a3.y; acc[14]+=a3.z; acc[15]+=a3.w;
        xr[i][0]=packh2(a0.x,a0.y); xr[i][1]=packh2(a0.z,a0.w);
        xr[i][2]=packh2(a1.x,a1.y); xr[i][3]=packh2(a1.z,a1.w);
        xr[i][4]=packh2(a2.x,a2.y); xr[i][5]=packh2(a2.z,a2.w);
        xr[i][6]=packh2(a3.x,a3.y); xr[i][7]=packh2(a3.z,a3.w);
    }
    #pragma unroll
    for (int i = 0; i < LDS_ROWS; ++i) {
        const int row = w * ROWS_PER_WAVE + REG_ROWS + i;
        const float* rp = x + (rowBase + row) * 1024 + lane * 16;
        f4 a0 = __builtin_nontemporal_load((const f4*)rp);
        f4 a1 = __builtin_nontemporal_load((const f4*)(rp + 4));
        f4 a2 = __builtin_nontemporal_load((const f4*)(rp + 8));
        f4 a3 = __builtin_nontemporal_load((const f4*)(rp + 12));
        acc[0]+=a0.x; acc[1]+=a0.y; acc[2]+=a0.z; acc[3]+=a0.w;
        acc[4]+=a1.x; acc[5]+=a1.y; acc[6]+=a1.z; acc[7]+=a1.w;
        acc[8]+=a2.x; acc[9]+=a2.y; acc[10]+=a2.z; acc[11]+=a2.w;
        acc[12]+=a3.x; acc[13]+=a3.y; acc[14]+=a3.z; acc[15]+=a3.w;
        const int slot = w * LDS_ROWS + i;
        ldsU[slot*512 + 0*64 + lane] = packh2(a0.x,a0.y);
        ldsU[slot*512 + 1*64 + lane] = packh2(a0.z,a0.w);
        ldsU[slot*512 + 2*64 + lane] = packh2(a1.x,a1.y);
        ldsU[slot*512 + 3*64 + lane] = packh2(a1.z,a1.w);
        ldsU[slot*512 + 4*64 + lane] = packh2(a2.x,a2.y);
        ldsU[slot*512 + 5*64 + lane] = packh2(a2.z,a2.w);
        ldsU[slot*512 + 6*64 + lane] = packh2(a3.x,a3.y);
        ldsU[slot*512 + 7*64 + lane] = packh2(a3.z,a3.w);
    }
    #pragma unroll
    for (int i = 0; i < WS_ROWS; ++i) {
        const int row = w * ROWS_PER_WAVE + REG_ROWS + LDS_ROWS + i;
        const float* rp = x + (rowBase + row) * 1024 + lane * 16;
        f4 a0 = __builtin_nontemporal_load((const f4*)rp);
        f4 a1 = __builtin_nontemporal_load((const f4*)(rp + 4));
        f4 a2 = __builtin_nontemporal_load((const f4*)(rp + 8));
        f4 a3 = __builtin_nontemporal_load((const f4*)(rp + 12));
        acc[0]+=a0.x; acc[1]+=a0.y; acc[2]+=a0.z; acc[3]+=a0.w;
        acc[4]+=a1.x; acc[5]+=a1.y; acc[6]+=a1.z; acc[7]+=a1.w;
        acc[8]+=a2.x; acc[9]+=a2.y; acc[10]+=a2.z; acc[11]+=a2.w;
        acc[12]+=a3.x; acc[13]+=a3.y; acc[14]+=a3.z; acc[15]+=a3.w;
        u32* gp = xh + ((size_t)(blk * 8 + w) * WS_ROWS + i) * 512 + lane;
        gp[0*64]=packh2(a0.x,a0.y); gp[1*64]=packh2(a0.z,a0.w);
        gp[2*64]=packh2(a1.x,a1.y); gp[3*64]=packh2(a1.z,a1.w);
        gp[4*64]=packh2(a2.x,a2.y); gp[5*64]=packh2(a2.z,a2.w);
        gp[6*64]=packh2(a3.x,a3.y); gp[7*64]=packh2(a3.z,a3.w);
    }
    phase_epilogue(acc, red, pA, cnt0, flag0, bias, vbuf0, 1.f/64.f, false,
                   b, blk, tid, lane, w, n2s, sLast);

    // ---------------- phase 1 ----------------
    float vl[16];
    wait_flag(flag0, b, tid);
    #pragma unroll
    for (int d = 0; d < 16; ++d) vl[d] = ald(vbuf0 + (size_t)b*1024 + lane*16 + d);

    weighted_phase(xr, ldsU, xh, vl, acc, blk, w, lane);
    phase_epilogue(acc, red, pB, cnt1, flag1, bias, vbuf1, 1.f, false,
                   b, blk, tid, lane, w, n2s, sLast);

    // ---------------- phase 2 ----------------
    wait_flag(flag1, b, tid);
    #pragma unroll
    for (int d = 0; d < 16; ++d) vl[d] += ald(vbuf1 + (size_t)b*1024 + lane*16 + d);

    weighted_phase(xr, ldsU, xh, vl, acc, blk, w, lane);
    phase_epilogue(acc, red, pC, cnt2, nullptr, bias, out, 1.f, true,
                   b, blk, tid, lane, w, n2s, sLast);
}

// ================= fallback (non-cooperative), correctness insurance =================
#define FCH 16
#define FRPC 128

template <int MODE>
__global__ __launch_bounds__(256) void fb_pass(
    const float* __restrict__ x, const float* __restrict__ v0,
    const float* __restrict__ v1, float* __restrict__ pout)
{
    const int blk = blockIdx.x, b = blk / FCH, c = blk % FCH;
    const int tid = threadIdx.x, lane = tid & 63, w = tid >> 6;
    float vl[16], acc[16];
    #pragma unroll
    for (int d = 0; d < 16; ++d) acc[d] = 0.f;
    if (MODE >= 1) {
        #pragma unroll
        for (int d = 0; d < 16; ++d) {
            vl[d] = v0[(size_t)b*1024 + lane*16 + d];
            if (MODE == 2) vl[d] += v1[(size_t)b*1024 + lane*16 + d];
        }
    }
    for (int i = 0; i < 32; ++i) {
        const size_t r = (size_t)b * NIN + c * FRPC + w * 32 + i;
        const float* rp = x + r * 1024 + lane * 16;
        float xx[16];
        #pragma unroll
        for (int kk = 0; kk < 4; ++kk) {
            f4 t = ((const f4*)rp)[kk];
            xx[4*kk]=t.x; xx[4*kk+1]=t.y; xx[4*kk+2]=t.z; xx[4*kk+3]=t.w;
        }
        if (MODE == 0) {
            #pragma unroll
            for (int d = 0; d < 16; ++d) acc[d] += xx[d];
        } else soft_acc(xx, vl, acc);
    }
    __shared__ f4 red[4 * 256];
    #pragma unroll
    for (int k = 0; k < 4; ++k)
        red[(w*4+k)*64 + lane] = f4{acc[4*k],acc[4*k+1],acc[4*k+2],acc[4*k+3]};
    __syncthreads();
    if (tid < 256) {
        f4 s = (red[tid] + red[256+tid]) + (red[512+tid] + red[768+tid]);
        *(f4*)(pout + (size_t)blk*1024 + tid*4) = s;
    }
}

__global__ __launch_bounds__(256) void fb_red(
    const float* __restrict__ pin, const float* __restrict__ bias,
    float* __restrict__ vout, float scale)
{
    const int b = blockIdx.x, tid = threadIdx.x;
    __shared__ float n2s[256];
    f4 s = f4{0.f,0.f,0.f,0.f};
    for (int c = 0; c < FCH; ++c)
        s += *(const f4*)(pin + (size_t)(b*FCH+c)*1024 + tid*4);
    const int n = tid & 63, k = tid >> 6;
    s = s * scale + *(const f4*)(bias + n*16 + 4*k);
    n2s[tid] = s.x*s.x + s.y*s.y + s.z*s.z + s.w*s.w;
    __syncthreads();
    const float n2 = n2s[n] + n2s[64+n] + n2s[128+n] + n2s[192+n];
    const float kf = n2 / ((1.f+n2) * sqrtf(n2 + 1e-7f));
    s *= kf;
    *(f4*)(vout + (size_t)b*1024 + n*16 + 4*k) = s;
}

extern "C" void kernel_launch(void* const* d_in, const int* in_sizes, int n_in,
                              void* d_out, int out_size, void* d_ws, size_t ws_size,
                              hipStream_t stream) {
    const float* x    = (const float*)d_in[0];
    const float* bias = (const float*)d_in[1];
    float* out        = (float*)d_out;
    char* wsb         = (char*)d_ws;

    int* cnt0  = (int*)(wsb + 0);
    int* cnt1  = (int*)(wsb + 128);
    int* cnt2  = (int*)(wsb + 256);
    int* flag0 = (int*)(wsb + 384);
    int* flag1 = (int*)(wsb + 512);
    float* vbuf0 = (float*)(wsb + 1024);
    float* vbuf1 = (float*)(wsb + 1024 + 131072);
    float* pA    = (float*)(wsb + 1024 + 2*131072);
    float* pB    = pA + 262144;
    float* pC    = pB + 262144;
    u32*   xh    = (u32*)(pC + 262144);

    hipError_t e1 = hipFuncSetAttribute((const void*)router_persistent,
        hipFuncAttributeMaxDynamicSharedMemorySize, DYN_LDS_BYTES);
    if (e1 == hipSuccess) {
        hipMemsetAsync(wsb, 0, 1024, stream);   // zero counters/flags each call
        void* args[] = {(void*)&x, (void*)&bias, (void*)&out,
                        (void*)&cnt0, (void*)&cnt1, (void*)&cnt2,
                        (void*)&flag0, (void*)&flag1,
                        (void*)&vbuf0, (void*)&vbuf1,
                        (void*)&pA, (void*)&pB, (void*)&pC, (void*)&xh};
        hipError_t e2 = hipLaunchCooperativeKernel((void*)router_persistent,
            dim3(NBLK), dim3(TPB), args, DYN_LDS_BYTES, stream);
        if (e2 == hipSuccess) return;
    }

    // fallback: 6-kernel f32 path
    float* fbP0 = (float*)wsb;                  // 512*1024 floats = 2 MB
    float* fbP1 = fbP0 + 524288;
    float* fbP2 = fbP1 + 524288;
    float* fv0  = fbP2 + 524288;
    float* fv1  = fv0 + 32768;
    fb_pass<0><<<BB*FCH, 256, 0, stream>>>(x, nullptr, nullptr, fbP0);
    fb_red<<<BB, 256, 0, stream>>>(fbP0, bias, fv0, 1.f/64.f);
    fb_pass<1><<<BB*FCH, 256, 0, stream>>>(x, fv0, nullptr, fbP1);
    fb_red<<<BB, 256, 0, stream>>>(fbP1, bias, fv1, 1.f);
    fb_pass<2><<<BB*FCH, 256, 0, stream>>>(x, fv0, fv1, fbP2);
    fb_red<<<BB, 256, 0, stream>>>(fbP2, bias, out, 1.f);
}

// Round 9
// 260.566 us; speedup vs baseline: 2.1062x; 2.1062x over previous
//
#include <hip/hip_runtime.h>
#include <math.h>

#define BB 32
#define NIN 2048
#define NBLK 256          // 1 block per CU (cooperative)
#define TPB 512           // 8 waves
#define BLKS_PER_B 8      // NBLK / BB
#define ROWS_PER_BLK 256  // NIN / BLKS_PER_B
#define ROWS_PER_WAVE 32
#define REG_ROWS 12       // rows in VGPRs per wave (12*8 = 96 VGPRs)
#define LDS_ROWS 8        // rows in LDS per wave (64/block = 128 KiB)
#define WS_ROWS 12        // rows spilled to fp16 workspace per wave

#define LDS_DATA_U32 (8 * LDS_ROWS * 512)   // 32768 u32 = 128 KiB
#define RED_OFF LDS_DATA_U32
#define RED_U32 4096                         // 1024 f4 = 16 KiB
#define VSM_OFF (RED_OFF + RED_U32)
#define VSM_U32 1024                         // 4 KiB
#define DYN_LDS_BYTES ((VSM_OFF + VSM_U32) * 4)   // 151552 B

typedef float f4 __attribute__((ext_vector_type(4)));
typedef float f2 __attribute__((ext_vector_type(2)));
typedef _Float16 h2 __attribute__((ext_vector_type(2)));
typedef unsigned int u32;
typedef u32 u32x4 __attribute__((ext_vector_type(4)));

#define AS __HIP_MEMORY_SCOPE_AGENT

__device__ __forceinline__ u32 packh2(float a, float b) {
    h2 h = { (_Float16)a, (_Float16)b };
    u32 u; __builtin_memcpy(&u, &h, 4); return u;
}
__device__ __forceinline__ f2 unph2(u32 u) {
    h2 h; __builtin_memcpy(&h, &u, 4);
    return __builtin_convertvector(h, f2);
}
__device__ __forceinline__ void ast(float* p, float v) {
    __hip_atomic_store(p, v, __ATOMIC_RELAXED, AS);
}
__device__ __forceinline__ float ald(float* p) {
    return __hip_atomic_load(p, __ATOMIC_RELAXED, AS);
}

__device__ __forceinline__ void unp16(u32x4 lo, u32x4 hi, float (&xx)[16]) {
    #pragma unroll
    for (int kk = 0; kk < 4; ++kk) {
        f2 a = unph2(lo[kk]); xx[2*kk]   = a.x; xx[2*kk+1]   = a.y;
        f2 b = unph2(hi[kk]); xx[8+2*kk] = b.x; xx[8+2*kk+1] = b.y;
    }
}

// lane == n_out; xx/vl/acc are the 16 d-values of this lane's n_out
__device__ __forceinline__ void soft_acc(const float (&xx)[16], const float (&vl)[16],
                                         float (&acc)[16]) {
    float l = 0.f;
    #pragma unroll
    for (int d = 0; d < 16; ++d) l = fmaf(xx[d], vl[d], l);
    const float e = __expf(l);      // max-free: ||v|| <= 2, |l| small, safe in f32
    float p = e;
    #pragma unroll
    for (int o = 1; o <= 32; o <<= 1) p += __shfl_xor(p, o);   // 64-way denom
    const float a = e * __builtin_amdgcn_rcpf(p);
    #pragma unroll
    for (int d = 0; d < 16; ++d) acc[d] = fmaf(xx[d], a, acc[d]);
}

// block-reduce acc -> partials; last arriving block of batch b reduces, squashes,
// stores v (atomic) or out (plain), raises flag.
__device__ __forceinline__ void phase_epilogue(
    float (&acc)[16], u32* smem, float* pX, int* cnt, int* flag,
    const float* bias, float* vdst, float scale, bool plainOut,
    int b, int blk, int tid, int lane, int w, float* n2s, int* sLastP)
{
    f4* red = (f4*)(smem + RED_OFF);
    __syncthreads();                       // red reuse guard
    if (w < 4) {
        #pragma unroll
        for (int k = 0; k < 4; ++k)
            red[(w*4+k)*64 + lane] = f4{acc[4*k], acc[4*k+1], acc[4*k+2], acc[4*k+3]};
    }
    __syncthreads();
    if (w >= 4) {
        #pragma unroll
        for (int k = 0; k < 4; ++k) {
            const int idx = ((w-4)*4+k)*64 + lane;
            f4 t = red[idx];
            red[idx] = t + f4{acc[4*k], acc[4*k+1], acc[4*k+2], acc[4*k+3]};
        }
    }
    __syncthreads();
    if (tid < 256) {
        f4 s = (red[tid] + red[256+tid]) + (red[512+tid] + red[768+tid]);
        float* dst = pX + (size_t)blk * 1024 + tid * 4;
        ast(dst, s.x); ast(dst+1, s.y); ast(dst+2, s.z); ast(dst+3, s.w);
    }
    __syncthreads();
    if (tid == 0) {
        int old = __hip_atomic_fetch_add(&cnt[b], 1, __ATOMIC_ACQ_REL, AS);
        *sLastP = (old == BLKS_PER_B - 1);
    }
    __syncthreads();
    if (*sLastP) {                         // block-uniform
        f4 s = f4{0.f, 0.f, 0.f, 0.f};
        const int n = tid & 63, k = tid >> 6;
        if (tid < 256) {
            #pragma unroll
            for (int cb = 0; cb < BLKS_PER_B; ++cb) {
                float* src = pX + (size_t)(b * BLKS_PER_B + cb) * 1024 + tid * 4;
                s += f4{ald(src), ald(src+1), ald(src+2), ald(src+3)};
            }
            const f4 bi = *(const f4*)(bias + n * 16 + 4 * k);
            s = s * scale + bi;
            n2s[tid] = s.x*s.x + s.y*s.y + s.z*s.z + s.w*s.w;
        }
        __syncthreads();
        if (tid < 256) {
            const float n2 = n2s[n] + n2s[64+n] + n2s[128+n] + n2s[192+n];
            const float kf = n2 / ((1.f + n2) * sqrtf(n2 + 1e-7f));
            s *= kf;
            float* d = vdst + (size_t)b * 1024 + n * 16 + 4 * k;
            if (plainOut) *(f4*)d = s;
            else { ast(d, s.x); ast(d+1, s.y); ast(d+2, s.z); ast(d+3, s.w); }
        }
        __syncthreads();
        if (flag && tid == 0)
            __hip_atomic_store(&flag[b], 1, __ATOMIC_RELEASE, AS);
    }
}

__device__ __forceinline__ void wait_flag(int* flag, int b, int tid) {
    if (tid == 0) {
        int guard = 0;
        while (__hip_atomic_load(&flag[b], __ATOMIC_ACQUIRE, AS) == 0 &&
               ++guard < (1 << 22))
            __builtin_amdgcn_s_sleep(8);
    }
    __syncthreads();
}

// stage v through LDS: 1024 atomic loads per block instead of 8192
__device__ __forceinline__ void load_v(u32* smem, float* vbuf, int b, int tid, int lane,
                                       float (&vl)[16], bool addTo)
{
    float* vsm = (float*)(smem + VSM_OFF);
    if (tid < 256) {
        float* src = vbuf + (size_t)b * 1024 + tid * 4;
        f4 t = f4{ald(src), ald(src+1), ald(src+2), ald(src+3)};
        *(f4*)(vsm + tid * 4) = t;
    }
    __syncthreads();
    #pragma unroll
    for (int d = 0; d < 16; ++d) {
        const float v = vsm[lane * 16 + d];
        vl[d] = addTo ? vl[d] + v : v;
    }
}

__device__ __forceinline__ void weighted_phase(
    const u32 (&xr)[REG_ROWS][8], const u32* ldsU, const u32* xh,
    const float (&vl)[16], float (&acc)[16], int blk, int w, int lane)
{
    #pragma unroll
    for (int d = 0; d < 16; ++d) acc[d] = 0.f;

    // issue first ws row early so it flies under the reg-row compute
    const u32* base = xh + ((size_t)(blk * 8 + w) * WS_ROWS) * 512 + lane * 8;
    u32x4 lo = *(const u32x4*)(base);
    u32x4 hi = *(const u32x4*)(base + 4);

    #pragma unroll
    for (int i = 0; i < REG_ROWS; ++i) {
        float xx[16];
        u32x4 rlo = u32x4{xr[i][0], xr[i][1], xr[i][2], xr[i][3]};
        u32x4 rhi = u32x4{xr[i][4], xr[i][5], xr[i][6], xr[i][7]};
        unp16(rlo, rhi, xx);
        soft_acc(xx, vl, acc);
    }
    #pragma unroll 2
    for (int j = 0; j < WS_ROWS; ++j) {
        const u32x4 clo = lo, chi = hi;
        if (j + 1 < WS_ROWS) {
            lo = *(const u32x4*)(base + (size_t)(j + 1) * 512);
            hi = *(const u32x4*)(base + (size_t)(j + 1) * 512 + 4);
        }
        float xx[16];
        unp16(clo, chi, xx);
        soft_acc(xx, vl, acc);
    }
    #pragma unroll 2
    for (int i = 0; i < LDS_ROWS; ++i) {
        const u32x4* p = (const u32x4*)&ldsU[(w * LDS_ROWS + i) * 512 + lane * 8];
        u32x4 llo = p[0], lhi = p[1];
        float xx[16];
        unp16(llo, lhi, xx);
        soft_acc(xx, vl, acc);
    }
}

__global__ __launch_bounds__(TPB) __attribute__((amdgpu_waves_per_eu(2, 2)))
void router_persistent(
    const float* __restrict__ x, const float* __restrict__ bias,
    float* __restrict__ out,
    int* cnt0, int* cnt1, int* cnt2, int* flag0, int* flag1,
    float* vbuf0, float* vbuf1, float* pA, float* pB, float* pC,
    u32* __restrict__ xh)
{
    extern __shared__ u32 smem[];
    u32* ldsU = smem;
    __shared__ float n2s[256];
    __shared__ int sLast;

    const int blk = blockIdx.x;
    const int b   = blk / BLKS_PER_B;
    const int cb  = blk % BLKS_PER_B;
    const int tid = threadIdx.x;
    const int lane = tid & 63, w = tid >> 6;

    const size_t rowBase = (size_t)(b * NIN + cb * ROWS_PER_BLK);

    u32 xr[REG_ROWS][8];
    float acc[16];
    #pragma unroll
    for (int d = 0; d < 16; ++d) acc[d] = 0.f;

    // ---------------- phase 0: one NT f32 read, plain sum, stash fp16 ----------------
    #pragma unroll
    for (int i = 0; i < REG_ROWS; ++i) {
        const float* rp = x + (rowBase + w * ROWS_PER_WAVE + i) * 1024 + lane * 16;
        f4 a0 = __builtin_nontemporal_load((const f4*)rp);
        f4 a1 = __builtin_nontemporal_load((const f4*)(rp + 4));
        f4 a2 = __builtin_nontemporal_load((const f4*)(rp + 8));
        f4 a3 = __builtin_nontemporal_load((const f4*)(rp + 12));
        acc[0]+=a0.x; acc[1]+=a0.y; acc[2]+=a0.z; acc[3]+=a0.w;
        acc[4]+=a1.x; acc[5]+=a1.y; acc[6]+=a1.z; acc[7]+=a1.w;
        acc[8]+=a2.x; acc[9]+=a2.y; acc[10]+=a2.z; acc[11]+=a2.w;
        acc[12]+=a3.x; acc[13]+=a3.y; acc[14]+=a3.z; acc[15]+=a3.w;
        xr[i][0]=packh2(a0.x,a0.y); xr[i][1]=packh2(a0.z,a0.w);
        xr[i][2]=packh2(a1.x,a1.y); xr[i][3]=packh2(a1.z,a1.w);
        xr[i][4]=packh2(a2.x,a2.y); xr[i][5]=packh2(a2.z,a2.w);
        xr[i][6]=packh2(a3.x,a3.y); xr[i][7]=packh2(a3.z,a3.w);
    }
    #pragma unroll 2
    for (int i = 0; i < LDS_ROWS; ++i) {
        const int row = w * ROWS_PER_WAVE + REG_ROWS + i;
        const float* rp = x + (rowBase + row) * 1024 + lane * 16;
        f4 a0 = __builtin_nontemporal_load((const f4*)rp);
        f4 a1 = __builtin_nontemporal_load((const f4*)(rp + 4));
        f4 a2 = __builtin_nontemporal_load((const f4*)(rp + 8));
        f4 a3 = __builtin_nontemporal_load((const f4*)(rp + 12));
        acc[0]+=a0.x; acc[1]+=a0.y; acc[2]+=a0.z; acc[3]+=a0.w;
        acc[4]+=a1.x; acc[5]+=a1.y; acc[6]+=a1.z; acc[7]+=a1.w;
        acc[8]+=a2.x; acc[9]+=a2.y; acc[10]+=a2.z; acc[11]+=a2.w;
        acc[12]+=a3.x; acc[13]+=a3.y; acc[14]+=a3.z; acc[15]+=a3.w;
        u32x4 plo = u32x4{packh2(a0.x,a0.y), packh2(a0.z,a0.w),
                          packh2(a1.x,a1.y), packh2(a1.z,a1.w)};
        u32x4 phi = u32x4{packh2(a2.x,a2.y), packh2(a2.z,a2.w),
                          packh2(a3.x,a3.y), packh2(a3.z,a3.w)};
        u32x4* dst = (u32x4*)&ldsU[(w * LDS_ROWS + i) * 512 + lane * 8];
        dst[0] = plo; dst[1] = phi;
    }
    #pragma unroll 2
    for (int i = 0; i < WS_ROWS; ++i) {
        const int row = w * ROWS_PER_WAVE + REG_ROWS + LDS_ROWS + i;
        const float* rp = x + (rowBase + row) * 1024 + lane * 16;
        f4 a0 = __builtin_nontemporal_load((const f4*)rp);
        f4 a1 = __builtin_nontemporal_load((const f4*)(rp + 4));
        f4 a2 = __builtin_nontemporal_load((const f4*)(rp + 8));
        f4 a3 = __builtin_nontemporal_load((const f4*)(rp + 12));
        acc[0]+=a0.x; acc[1]+=a0.y; acc[2]+=a0.z; acc[3]+=a0.w;
        acc[4]+=a1.x; acc[5]+=a1.y; acc[6]+=a1.z; acc[7]+=a1.w;
        acc[8]+=a2.x; acc[9]+=a2.y; acc[10]+=a2.z; acc[11]+=a2.w;
        acc[12]+=a3.x; acc[13]+=a3.y; acc[14]+=a3.z; acc[15]+=a3.w;
        u32x4 plo = u32x4{packh2(a0.x,a0.y), packh2(a0.z,a0.w),
                          packh2(a1.x,a1.y), packh2(a1.z,a1.w)};
        u32x4 phi = u32x4{packh2(a2.x,a2.y), packh2(a2.z,a2.w),
                          packh2(a3.x,a3.y), packh2(a3.z,a3.w)};
        u32x4* gp = (u32x4*)(xh + ((size_t)(blk * 8 + w) * WS_ROWS + i) * 512 + lane * 8);
        gp[0] = plo; gp[1] = phi;     // normal stores: stay L2-local for re-read
    }
    phase_epilogue(acc, smem, pA, cnt0, flag0, bias, vbuf0, 1.f/64.f, false,
                   b, blk, tid, lane, w, n2s, &sLast);

    // ---------------- phase 1 ----------------
    float vl[16];
    wait_flag(flag0, b, tid);
    load_v(smem, vbuf0, b, tid, lane, vl, false);
    weighted_phase(xr, ldsU, xh, vl, acc, blk, w, lane);
    phase_epilogue(acc, smem, pB, cnt1, flag1, bias, vbuf1, 1.f, false,
                   b, blk, tid, lane, w, n2s, &sLast);

    // ---------------- phase 2 ----------------
    wait_flag(flag1, b, tid);
    load_v(smem, vbuf1, b, tid, lane, vl, true);   // vl = v0 + v1
    weighted_phase(xr, ldsU, xh, vl, acc, blk, w, lane);
    phase_epilogue(acc, smem, pC, cnt2, nullptr, bias, out, 1.f, true,
                   b, blk, tid, lane, w, n2s, &sLast);
}

// ================= fallback (non-cooperative), correctness insurance =================
#define FCH 16
#define FRPC 128

template <int MODE>
__global__ __launch_bounds__(256) void fb_pass(
    const float* __restrict__ x, const float* __restrict__ v0,
    const float* __restrict__ v1, float* __restrict__ pout)
{
    const int blk = blockIdx.x, b = blk / FCH, c = blk % FCH;
    const int tid = threadIdx.x, lane = tid & 63, w = tid >> 6;
    float vl[16], acc[16];
    #pragma unroll
    for (int d = 0; d < 16; ++d) acc[d] = 0.f;
    if (MODE >= 1) {
        #pragma unroll
        for (int d = 0; d < 16; ++d) {
            vl[d] = v0[(size_t)b*1024 + lane*16 + d];
            if (MODE == 2) vl[d] += v1[(size_t)b*1024 + lane*16 + d];
        }
    }
    for (int i = 0; i < 32; ++i) {
        const size_t r = (size_t)b * NIN + c * FRPC + w * 32 + i;
        const float* rp = x + r * 1024 + lane * 16;
        float xx[16];
        #pragma unroll
        for (int kk = 0; kk < 4; ++kk) {
            f4 t = ((const f4*)rp)[kk];
            xx[4*kk]=t.x; xx[4*kk+1]=t.y; xx[4*kk+2]=t.z; xx[4*kk+3]=t.w;
        }
        if (MODE == 0) {
            #pragma unroll
            for (int d = 0; d < 16; ++d) acc[d] += xx[d];
        } else soft_acc(xx, vl, acc);
    }
    __shared__ f4 red[4 * 256];
    #pragma unroll
    for (int k = 0; k < 4; ++k)
        red[(w*4+k)*64 + lane] = f4{acc[4*k],acc[4*k+1],acc[4*k+2],acc[4*k+3]};
    __syncthreads();
    if (tid < 256) {
        f4 s = (red[tid] + red[256+tid]) + (red[512+tid] + red[768+tid]);
        *(f4*)(pout + (size_t)blk*1024 + tid*4) = s;
    }
}

__global__ __launch_bounds__(256) void fb_red(
    const float* __restrict__ pin, const float* __restrict__ bias,
    float* __restrict__ vout, float scale)
{
    const int b = blockIdx.x, tid = threadIdx.x;
    __shared__ float n2s[256];
    f4 s = f4{0.f,0.f,0.f,0.f};
    for (int c = 0; c < FCH; ++c)
        s += *(const f4*)(pin + (size_t)(b*FCH+c)*1024 + tid*4);
    const int n = tid & 63, k = tid >> 6;
    s = s * scale + *(const f4*)(bias + n*16 + 4*k);
    n2s[tid] = s.x*s.x + s.y*s.y + s.z*s.z + s.w*s.w;
    __syncthreads();
    const float n2 = n2s[n] + n2s[64+n] + n2s[128+n] + n2s[192+n];
    const float kf = n2 / ((1.f+n2) * sqrtf(n2 + 1e-7f));
    s *= kf;
    *(f4*)(vout + (size_t)b*1024 + n*16 + 4*k) = s;
}

extern "C" void kernel_launch(void* const* d_in, const int* in_sizes, int n_in,
                              void* d_out, int out_size, void* d_ws, size_t ws_size,
                              hipStream_t stream) {
    const float* x    = (const float*)d_in[0];
    const float* bias = (const float*)d_in[1];
    float* out        = (float*)d_out;
    char* wsb         = (char*)d_ws;

    int* cnt0  = (int*)(wsb + 0);
    int* cnt1  = (int*)(wsb + 128);
    int* cnt2  = (int*)(wsb + 256);
    int* flag0 = (int*)(wsb + 384);
    int* flag1 = (int*)(wsb + 512);
    float* vbuf0 = (float*)(wsb + 1024);
    float* vbuf1 = (float*)(wsb + 1024 + 131072);
    float* pA    = (float*)(wsb + 1024 + 2*131072);
    float* pB    = pA + NBLK * 1024;
    float* pC    = pB + NBLK * 1024;
    u32*   xh    = (u32*)(pC + NBLK * 1024);   // 256*8*12*512*4 B = 48 MiB

    hipError_t e1 = hipFuncSetAttribute((const void*)router_persistent,
        hipFuncAttributeMaxDynamicSharedMemorySize, DYN_LDS_BYTES);
    if (e1 == hipSuccess) {
        hipMemsetAsync(wsb, 0, 1024, stream);   // zero counters/flags each call
        void* args[] = {(void*)&x, (void*)&bias, (void*)&out,
                        (void*)&cnt0, (void*)&cnt1, (void*)&cnt2,
                        (void*)&flag0, (void*)&flag1,
                        (void*)&vbuf0, (void*)&vbuf1,
                        (void*)&pA, (void*)&pB, (void*)&pC, (void*)&xh};
        hipError_t e2 = hipLaunchCooperativeKernel((void*)router_persistent,
            dim3(NBLK), dim3(TPB), args, DYN_LDS_BYTES, stream);
        if (e2 == hipSuccess) return;
    }

    // fallback: 6-kernel f32 path
    float* fbP0 = (float*)wsb;
    float* fbP1 = fbP0 + 524288;
    float* fbP2 = fbP1 + 524288;
    float* fv0  = fbP2 + 524288;
    float* fv1  = fv0 + 32768;
    fb_pass<0><<<BB*FCH, 256, 0, stream>>>(x, nullptr, nullptr, fbP0);
    fb_red<<<BB, 256, 0, stream>>>(fbP0, bias, fv0, 1.f/64.f);
    fb_pass<1><<<BB*FCH, 256, 0, stream>>>(x, fv0, nullptr, fbP1);
    fb_red<<<BB, 256, 0, stream>>>(fbP1, bias, fv1, 1.f);
    fb_pass<2><<<BB*FCH, 256, 0, stream>>>(x, fv0, fv1, fbP2);
    fb_red<<<BB, 256, 0, stream>>>(fbP2, bias, out, 1.f);
}

// Round 10
// 179.764 us; speedup vs baseline: 3.0530x; 1.4495x over previous
//
#include <hip/hip_runtime.h>
#include <math.h>

#define BB 32
#define NIN 2048
#define CH 16            // chunks (blocks) per batch element
#define RPC 128          // rows per block (NIN / CH)
#define TPB 512          // 8 waves
#define NW 8

typedef float    f4 __attribute__((ext_vector_type(4)));
typedef float    f8 __attribute__((ext_vector_type(8)));
typedef _Float16 h4 __attribute__((ext_vector_type(4)));
typedef _Float16 h8 __attribute__((ext_vector_type(8)));

#define AS __HIP_MEMORY_SCOPE_AGENT

__device__ __forceinline__ void ast(float* p, float v) {
    __hip_atomic_store(p, v, __ATOMIC_RELAXED, AS);
}
__device__ __forceinline__ float ald(const float* p) {
    return __hip_atomic_load((float*)p, __ATOMIC_RELAXED, AS);
}

__device__ __forceinline__ float dot8(f8 a, f8 b) {
    float s01 = fmaf(a[1], b[1], a[0] * b[0]);
    float s23 = fmaf(a[3], b[3], a[2] * b[2]);
    float s45 = fmaf(a[5], b[5], a[4] * b[4]);
    float s67 = fmaf(a[7], b[7], a[6] * b[6]);
    return (s01 + s23) + (s45 + s67);
}

// Caller wrote its block partial into red[NW*256] (f4 index = flat (n*16+d)/4).
// Store to pX[blk]; last arriving block of batch b reduces all CH partials,
// applies scale+bias+squash, writes v (atomic) or out (plain).
__device__ __forceinline__ void tail_reduce(
    f4* red, float* pX, int* cnt, const float* bias,
    float* vdst, float scale, bool plainOut, int b, int blk, int tid)
{
    __syncthreads();
    if (tid < 256) {
        f4 s = (red[tid] + red[256 + tid]) + (red[512 + tid] + red[768 + tid]);
        s += (red[1024 + tid] + red[1280 + tid]) + (red[1536 + tid] + red[1792 + tid]);
        float* dst = pX + (size_t)blk * 1024 + tid * 4;
        ast(dst, s.x); ast(dst + 1, s.y); ast(dst + 2, s.z); ast(dst + 3, s.w);
    }
    __syncthreads();   // all partial stores drained before the count
    __shared__ int sLast;
    if (tid == 0)
        sLast = (__hip_atomic_fetch_add(&cnt[b], 1, __ATOMIC_ACQ_REL, AS) == CH - 1);
    __syncthreads();
    if (!sLast) return;

    if (tid < 256) {
        f4 t = f4{0.f, 0.f, 0.f, 0.f};
        #pragma unroll 4
        for (int c = 0; c < CH; ++c) {
            const float* src = pX + (size_t)(b * CH + c) * 1024 + tid * 4;
            t += f4{ald(src), ald(src + 1), ald(src + 2), ald(src + 3)};
        }
        t = t * scale + ((const f4*)bias)[tid];
        float n2 = t.x * t.x + t.y * t.y + t.z * t.z + t.w * t.w;
        n2 += __shfl_xor(n2, 1);   // quad (tids 4n..4n+3) covers n's 16 floats
        n2 += __shfl_xor(n2, 2);
        const float kf = n2 / ((1.f + n2) * sqrtf(n2 + 1e-7f));
        t *= kf;
        float* d = vdst + (size_t)b * 1024 + tid * 4;
        if (plainOut) *(f4*)d = t;
        else { ast(d, t.x); ast(d + 1, t.y); ast(d + 2, t.z); ast(d + 3, t.w); }
    }
}

// ---------------- pass 0: NT f32 read, plain sum, emit fp16 copy, tail -> v0 ---------
__global__ __launch_bounds__(TPB, 4) void pass0_kernel(
    const float* __restrict__ x, h4* __restrict__ xh,
    float* __restrict__ pA, int* __restrict__ cnt0,
    const float* __restrict__ bias, float* __restrict__ v0)
{
    const int blk = blockIdx.x;
    const int chunk = blk & (CH - 1);
    const int b = blk >> 4;
    const int tid = threadIdx.x;
    const int lane = tid & 63, wave = tid >> 6;

    f4 acc[4];
    #pragma unroll
    for (int j = 0; j < 4; ++j) acc[j] = f4{0.f, 0.f, 0.f, 0.f};

    const size_t row0 = (size_t)b * NIN + (size_t)chunk * RPC;

    #pragma unroll 2
    for (int r = wave; r < RPC; r += NW) {
        const f4* rp = (const f4*)x + (row0 + r) * 256;
        h4* hp = xh + (row0 + r) * 256;
        #pragma unroll
        for (int j = 0; j < 4; ++j) {
            f4 xv = __builtin_nontemporal_load(&rp[j * 64 + lane]);  // keep f32 out of L3
            acc[j] += xv;
            hp[j * 64 + lane] = __builtin_convertvector(xv, h4);     // xh may stay L3-hot
        }
    }

    __shared__ f4 red[NW * 256];
    #pragma unroll
    for (int j = 0; j < 4; ++j) red[wave * 256 + j * 64 + lane] = acc[j];
    tail_reduce(red, pA, cnt0, bias, v0, 1.0f / 64.0f, false, b, blk, tid);
}

// ---------------- passes 1/2: fp16 stream, softmax-weighted sum, tail -> v1 / out ----
// Lane layout: idx = j*64+lane (j=0,1); n_out = idx>>1, d-half = idx&1; lane pair
// (lane, lane^1) holds the full 16-d row of one n_out.
// MODE 2 uses dot(x,v0)+dot(x,v1) = dot(x, v0+v1).
template <int MODE>
__global__ __launch_bounds__(TPB, 4) void pass_kernel(
    const h8* __restrict__ xh,
    const float* __restrict__ v0g, const float* __restrict__ v1g,
    const float* __restrict__ bias,
    float* __restrict__ pX, int* __restrict__ cnt,
    float* __restrict__ vdst)
{
    const int blk = blockIdx.x;
    const int chunk = blk & (CH - 1);
    const int b = blk >> 4;
    const int tid = threadIdx.x;
    const int lane = tid & 63, wave = tid >> 6;

    const size_t row0 = (size_t)b * NIN + (size_t)chunk * RPC;

    // prefetch first row while v loads arrive
    const h8* hp0 = xh + (row0 + wave) * 128;
    h8 hx0 = hp0[lane];
    h8 hx1 = hp0[64 + lane];

    f8 vaf[2];
    #pragma unroll
    for (int j = 0; j < 2; ++j) {
        const int idx = j * 64 + lane;
        vaf[j] = *(const f8*)(v0g + (size_t)b * 1024 + idx * 8);
        if (MODE == 2) vaf[j] += *(const f8*)(v1g + (size_t)b * 1024 + idx * 8);
    }

    f8 acc0 = {0.f, 0.f, 0.f, 0.f, 0.f, 0.f, 0.f, 0.f};
    f8 acc1 = acc0;

    #pragma unroll 2
    for (int r = wave; r < RPC; r += NW) {
        const f8 x0 = __builtin_convertvector(hx0, f8);
        const f8 x1 = __builtin_convertvector(hx1, f8);
        if (r + NW < RPC) {
            const h8* np = xh + (row0 + r + NW) * 128;
            hx0 = np[lane];
            hx1 = np[64 + lane];
        }

        float d0 = dot8(x0, vaf[0]);
        float d1 = dot8(x1, vaf[1]);
        d0 += __shfl_xor(d0, 1);   // combine the two d-halves of each n
        d1 += __shfl_xor(d1, 1);

        // max-free softmax: |logit| bounded (||v||<2), e^|l| safe in f32
        const float e0 = __expf(d0), e1 = __expf(d1);
        float p = e0 + e1;
        #pragma unroll
        for (int o = 2; o <= 32; o <<= 1) p += __shfl_xor(p, o);  // each n once
        const float inv = __builtin_amdgcn_rcpf(p);
        const float a0 = e0 * inv, a1 = e1 * inv;
        #pragma unroll
        for (int k = 0; k < 8; ++k) acc0[k] = fmaf(x0[k], a0, acc0[k]);
        #pragma unroll
        for (int k = 0; k < 8; ++k) acc1[k] = fmaf(x1[k], a1, acc1[k]);
    }

    __shared__ f4 red[NW * 256];
    // flat float offset for idx is idx*8+k == n*16+d -> f4 slots 2*idx, 2*idx+1
    *(f8*)(&red[wave * 256 + lane * 2])       = acc0;
    *(f8*)(&red[wave * 256 + 128 + lane * 2]) = acc1;
    tail_reduce(red, pX, cnt, bias, vdst, 1.0f, MODE == 2, b, blk, tid);
}

extern "C" void kernel_launch(void* const* d_in, const int* in_sizes, int n_in,
                              void* d_out, int out_size, void* d_ws, size_t ws_size,
                              hipStream_t stream) {
    const float* x    = (const float*)d_in[0];
    const float* bias = (const float*)d_in[1];
    float* out        = (float*)d_out;
    char* wsb         = (char*)d_ws;

    int*   cnt0 = (int*)(wsb + 0);
    int*   cnt1 = (int*)(wsb + 128);
    int*   cnt2 = (int*)(wsb + 256);
    float* v0   = (float*)(wsb + 1024);
    float* v1   = v0 + BB * 1024;                 // 128 KiB each
    float* pA   = v1 + BB * 1024;                 // BB*CH*1024 f = 2 MiB each
    float* pB   = pA + (size_t)BB * CH * 1024;
    float* pC   = pB + (size_t)BB * CH * 1024;
    h4*    xh   = (h4*)(pC + (size_t)BB * CH * 1024);   // 128 MiB fp16 copy

    hipMemsetAsync(wsb, 0, 1024, stream);   // zero counters every call (deterministic)

    const int GRID = BB * CH;   // 512
    pass0_kernel<<<GRID, TPB, 0, stream>>>(x, xh, pA, cnt0, bias, v0);
    pass_kernel<1><<<GRID, TPB, 0, stream>>>((const h8*)xh, v0, nullptr, bias,
                                             pB, cnt1, v1);
    pass_kernel<2><<<GRID, TPB, 0, stream>>>((const h8*)xh, v0, v1, bias,
                                             pC, cnt2, out);
}

// Round 11
// 116.326 us; speedup vs baseline: 4.7179x; 1.5453x over previous
//
#include <hip/hip_runtime.h>
#include <math.h>

#define BB 32
#define NIN 2048
#define NOUT 64
#define DD 16
#define CH 16            // chunks per batch element
#define RPC 128          // rows per chunk (NIN / CH)
#define TPB 512          // 8 waves per block; grid = BB*CH = 512 blocks

typedef float    f4 __attribute__((ext_vector_type(4)));
typedef float    f8 __attribute__((ext_vector_type(8)));
typedef _Float16 h4 __attribute__((ext_vector_type(4)));
typedef _Float16 h8 __attribute__((ext_vector_type(8)));

__device__ __forceinline__ float dot8(f8 a, f8 b) {
    // depth-3 tree instead of 8-deep fma chain
    float s01 = fmaf(a[1], b[1], a[0] * b[0]);
    float s23 = fmaf(a[3], b[3], a[2] * b[2]);
    float s45 = fmaf(a[5], b[5], a[4] * b[4]);
    float s67 = fmaf(a[7], b[7], a[6] * b[6]);
    return (s01 + s23) + (s45 + s67);
}

// ---------------- pass 0: stream f32 x (NT), emit fp16 copy, plain sum ----------------
__global__ __launch_bounds__(TPB, 4) void pass0_kernel(
    const float* __restrict__ x, h4* __restrict__ xh, f4* __restrict__ pout)
{
    const int blk  = blockIdx.x;
    const int chunk = blk & (CH - 1);
    const int b    = blk >> 4;
    const int tid  = threadIdx.x;
    const int lane = tid & 63, wave = tid >> 6;

    f4 acc[4];
    #pragma unroll
    for (int j = 0; j < 4; ++j) acc[j] = f4{0.f, 0.f, 0.f, 0.f};

    const size_t row0 = (size_t)b * NIN + (size_t)chunk * RPC;

    #pragma unroll 2
    for (int r = wave; r < RPC; r += 8) {
        const f4* rp = (const f4*)x + (row0 + r) * 256;
        h4* hp = xh + (row0 + r) * 256;
        #pragma unroll
        for (int j = 0; j < 4; ++j) {
            f4 xv = __builtin_nontemporal_load(&rp[j * 64 + lane]);  // keep f32 out of caches
            acc[j] += xv;
            hp[j * 64 + lane] = __builtin_convertvector(xv, h4);     // want xh L3-resident
        }
    }

    __shared__ f4 red[8][256];
    #pragma unroll
    for (int j = 0; j < 4; ++j) red[wave][j * 64 + lane] = acc[j];
    __syncthreads();
    if (tid < 256) {
        f4 s = red[0][tid];
        #pragma unroll
        for (int w = 1; w < 8; ++w) s += red[w][tid];
        pout[((size_t)(b * CH + chunk)) * 256 + tid] = s;
    }
}

// In-block reduction of previous pass's partials -> v (squash(sum*scale+bias)), into LDS.
__device__ __forceinline__ void compute_v(
    const f4* __restrict__ pin, const float* __restrict__ bias,
    int b, int tid, float scale, float* vsm, float* vout, int dowrite)
{
    if (tid < 256) {
        f4 s = pin[((size_t)b * CH) * 256 + tid];
        #pragma unroll
        for (int c = 1; c < CH; ++c) s += pin[((size_t)(b * CH + c)) * 256 + tid];
        const f4 bi = ((const f4*)bias)[tid];
        s = s * scale + bi;
        float n2 = s.x * s.x + s.y * s.y + s.z * s.z + s.w * s.w;
        n2 += __shfl_xor(n2, 1);
        n2 += __shfl_xor(n2, 2);
        const float k = n2 / ((1.0f + n2) * sqrtf(n2 + 1e-7f));
        const f4 v = s * k;
        *(f4*)(vsm + tid * 4) = v;
        if (dowrite) ((f4*)vout)[b * 256 + tid] = v;
    }
    __syncthreads();
}

// ---------------- passes 1/2: fp16 x, softmax-weighted sum ----------------
// Lane layout: idx = j*64+lane (j=0,1); covers n = idx>>1, d = (idx&1)*8 .. +7.
// Lane pair (lane, lane^1) holds the full 16-d row of one n.
// MODE 2 uses the identity dot(x,v0)+dot(x,v1) = dot(x, v0+v1).
template <int MODE>
__global__ __launch_bounds__(TPB, 4) void pass_kernel(
    const h8* __restrict__ xh,
    const f4* __restrict__ pin,
    const float* __restrict__ bias,
    const float* __restrict__ v0g,   // MODE2: v0 from global
    float* __restrict__ v0out,       // MODE1: write v0 (chunk==0 blocks)
    f4* __restrict__ pout)
{
    const int blk  = blockIdx.x;
    const int chunk = blk & (CH - 1);
    const int b    = blk >> 4;
    const int tid  = threadIdx.x;
    const int lane = tid & 63, wave = tid >> 6;

    __shared__ __align__(32) float vsm[1024];
    __shared__ __align__(32) float wsm[1024];
    __shared__ f4 red[8][256];

    const size_t row0 = (size_t)b * NIN + (size_t)chunk * RPC;

    // prefetch first row across the v-computation
    const h8* hp0 = xh + (row0 + wave) * 128;
    h8 hx0 = hp0[lane];
    h8 hx1 = hp0[64 + lane];

    if (MODE == 1) {
        compute_v(pin, bias, b, tid, 1.0f / 64.0f, vsm, v0out, chunk == 0);
    } else {
        if (tid < 256) *(f4*)(vsm + tid * 4) = ((const f4*)v0g)[b * 256 + tid];
        compute_v(pin, bias, b, tid, 1.0f, wsm, nullptr, 0);   // ends with __syncthreads
    }

    f8 vaf[2];
    #pragma unroll
    for (int j = 0; j < 2; ++j) {
        const int idx = j * 64 + lane;
        vaf[j] = *(const f8*)(vsm + idx * 8);
        if (MODE == 2) vaf[j] += *(const f8*)(wsm + idx * 8);   // v0 + v1
    }

    f8 acc0 = {0.f, 0.f, 0.f, 0.f, 0.f, 0.f, 0.f, 0.f};
    f8 acc1 = acc0;

    #pragma unroll 2
    for (int r = wave; r < RPC; r += 8) {
        const f8 x0 = __builtin_convertvector(hx0, f8);
        const f8 x1 = __builtin_convertvector(hx1, f8);
        if (r + 8 < RPC) {
            const h8* np = xh + (row0 + r + 8) * 128;
            hx0 = np[lane];
            hx1 = np[64 + lane];
        }

        float d0 = dot8(x0, vaf[0]);
        float d1 = dot8(x1, vaf[1]);
        d0 += __shfl_xor(d0, 1);   // combine the two d-halves of each n
        d1 += __shfl_xor(d1, 1);

        // max-free softmax: |logit| <= ~11 for N(0,1) data and ||v||<1, e^11 fine in f32
        const float e0 = __expf(d0), e1 = __expf(d1);
        float p = e0 + e1;
        #pragma unroll
        for (int o = 2; o <= 32; o <<= 1) p += __shfl_xor(p, o);  // each n exactly once
        const float inv = __builtin_amdgcn_rcpf(p);
        const float a0 = e0 * inv, a1 = e1 * inv;
        #pragma unroll
        for (int k = 0; k < 8; ++k) acc0[k] = fmaf(x0[k], a0, acc0[k]);
        #pragma unroll
        for (int k = 0; k < 8; ++k) acc1[k] = fmaf(x1[k], a1, acc1[k]);
    }

    // flat float offset of acc for idx is idx*8+k == n*16+d  -> f4 slots 2*idx, 2*idx+1
    *(f8*)(&red[wave][lane * 2])       = acc0;
    *(f8*)(&red[wave][128 + lane * 2]) = acc1;
    __syncthreads();
    if (tid < 256) {
        f4 s = red[0][tid];
        #pragma unroll
        for (int w = 1; w < 8; ++w) s += red[w][tid];
        pout[((size_t)(b * CH + chunk)) * 256 + tid] = s;
    }
}

// ---------------- final: reduce partials2 -> squash -> out ----------------
__global__ __launch_bounds__(256) void finish_kernel(
    const f4* __restrict__ pin, const float* __restrict__ bias, f4* __restrict__ out)
{
    const int b = blockIdx.x;
    const int tid = threadIdx.x;
    f4 s = pin[((size_t)b * CH) * 256 + tid];
    #pragma unroll
    for (int c = 1; c < CH; ++c) s += pin[((size_t)(b * CH + c)) * 256 + tid];
    s = s + ((const f4*)bias)[tid];
    float n2 = s.x * s.x + s.y * s.y + s.z * s.z + s.w * s.w;
    n2 += __shfl_xor(n2, 1);
    n2 += __shfl_xor(n2, 2);
    const float k = n2 / ((1.0f + n2) * sqrtf(n2 + 1e-7f));
    out[b * 256 + tid] = s * k;
}

extern "C" void kernel_launch(void* const* d_in, const int* in_sizes, int n_in,
                              void* d_out, int out_size, void* d_ws, size_t ws_size,
                              hipStream_t stream) {
    const float* x    = (const float*)d_in[0];
    const float* bias = (const float*)d_in[1];
    float* out        = (float*)d_out;

    const size_t XH_BYTES = (size_t)BB * NIN * 1024 * 2;   // 128 MiB fp16 copy
    h4*    xh = (h4*)d_ws;
    float* pA = (float*)((char*)d_ws + XH_BYTES);
    float* pB = pA + (size_t)BB * CH * 1024;
    float* pC = pB + (size_t)BB * CH * 1024;
    float* v0buf = pC + (size_t)BB * CH * 1024;

    pass0_kernel<<<BB * CH, TPB, 0, stream>>>(x, xh, (f4*)pA);
    pass_kernel<1><<<BB * CH, TPB, 0, stream>>>((const h8*)xh, (const f4*)pA, bias,
                                                nullptr, v0buf, (f4*)pB);
    pass_kernel<2><<<BB * CH, TPB, 0, stream>>>((const h8*)xh, (const f4*)pB, bias,
                                                v0buf, nullptr, (f4*)pC);
    finish_kernel<<<BB, 256, 0, stream>>>((const f4*)pC, bias, (f4*)out);
}